// Round 1
// baseline (90.596 us; speedup 1.0000x reference)
//
#include <hip/hip_runtime.h>
#include <math.h>

// Problem constants (match reference)
#define BB     256
#define KK     16
#define NBIN   128
#define GG     (NBIN * NBIN)       // 16384 bins per batch
#define SLICES 8                   // compute blocks per batch
#define NT1    256                 // threads per compute block
#define SPT    8                   // bins per thread (consecutive in j)
#define NT2    256                 // threads per normalize block

// Guaranteed single-instruction exp2. Argument is always <= 0, so
// v_exp_f32's flush-to-zero underflow for very negative inputs matches the
// reference semantics (exp(-huge) -> 0).
__device__ __forceinline__ float raw_exp2(float x) {
#if __has_builtin(__builtin_amdgcn_exp2f)
    return __builtin_amdgcn_exp2f(x);
#else
    float r;
    asm volatile("v_exp_f32 %0, %1\n\ts_nop 1" : "=v"(r) : "v"(x));
    return r;
#endif
}

// Kernel 1 — unnormalized splat + per-block partial sum.
//
// Occupancy was the bottleneck of the fused 1024-thread design: 256 blocks
// of 1024 = 1 block/CU = 4 waves/SIMD (50% cap), ~5x above the issue-bound
// floor (~4 us) => latency-bound. Here: 2048 blocks of 256 = 8 blocks/CU
// = 32 waves/CU = 8 waves/SIMD, VGPR capped at 64 (live set ~50).
//
// Block bb: batch b = bb>>3, slice p = bb&7 (rows [16p, 16p+16)).
// Thread t owns 8 CONSECUTIVE bins: row i = 16p + (t>>4), cols j = 8*(t&15)+e.
//   du fixed per (thread,k); dv = dvb + e*step (literal-const adds).
// Direct Horner evaluation of the quadratic in the ACTUAL dv (not expanded
// in the index) — same numerics discipline as the validated fused kernel,
// with u/v roles swapped so the 8 bins are contiguous => float4 stores.
__global__ __launch_bounds__(NT1, 8) void gmm_hist_partial(
    const float* __restrict__ mu,     // [B,K,2]
    const float* __restrict__ sigma,  // [B,K,2]
    const float* __restrict__ cov12,  // [B,K]
    const float* __restrict__ pi_,    // [B,K]
    float* __restrict__ out,          // [B,128,128] unnormalized
    float* __restrict__ psum)         // [B*SLICES] partial sums
{
    const int bb  = blockIdx.x;
    const int b   = bb >> 3;
    const int p   = bb & 7;
    const int tid = threadIdx.x;

    // Per-mixture params packed for ds_read_b128:
    //   s_par[2k+0] = {mu_u, mu_v, ia*cs, 2*ib*cs}
    //   s_par[2k+1] = {ic*cs, coef, 0, 0}
    __shared__ float4 s_par[2 * KK];
    __shared__ float  s_wsum[NT1 / 64];

    // ---- per-mixture precompute (threads 0..15), mirrors reference exactly ----
    if (tid < KK) {
        const int idx = b * KK + tid;
        const float m_u = mu[idx * 2 + 0];
        const float m_v = mu[idx * 2 + 1];
        const float su  = fmaxf(sigma[idx * 2 + 0], 0.001f);
        const float sv  = fmaxf(sigma[idx * 2 + 1], 0.001f);
        const float su2 = su * su;
        const float sv2 = sv * sv;
        const float c11 = su2 + 1e-6f;
        const float c22 = sv2 + 1e-6f;
        const float off = cov12[idx];
        const float det_full = c11 * c22 - off * off;
        const bool  valid    = (det_full > 0.0f);   // NaN compares false -> fallback
        const float det_safe = valid ? det_full : 1.0f;
        const float ia  = valid ? (c22 / det_safe) : (1.0f / su2);
        const float ib  = valid ? (-off / det_safe) : 0.0f;
        const float ic  = valid ? (c11 / det_safe) : (1.0f / sv2);
        const float det = valid ? det_full : (su2 * sv2);
        const float coef = pi_[idx] / (6.283185307179586f * sqrtf(det + 1e-6f));
        const float cs = -0.7213475204444817f;      // -0.5 * log2(e)
        s_par[2 * tid + 0] = make_float4(m_u, m_v, ia * cs, (2.0f * ib) * cs);
        s_par[2 * tid + 1] = make_float4(ic * cs, coef, 0.0f, 0.0f);
    }
    __syncthreads();

    const float step = 4.0f / 127.0f;               // linspace(-2,2,128) step
    const int   i    = (p << 4) + (tid >> 4);       // row 0..127
    const int   j0   = (tid & 15) << 3;             // first col of this thread
    const float ui   = -2.0f + (float)i  * step;
    const float v0   = -2.0f + (float)j0 * step;

    float acc[SPT];
    #pragma unroll
    for (int e = 0; e < SPT; ++e) acc[e] = 0.0f;

    // ---- main accumulation: 16 mixtures x 8 bins per thread ----
    // Per eval: v_add(dv) + v_fma + v_fma + v_exp + v_fma.
    #pragma unroll
    for (int k = 0; k < KK; ++k) {
        const float4 q0 = s_par[2 * k + 0];         // ds_read_b128
        const float4 q1 = s_par[2 * k + 1];         // ds_read_b128
        const float du   = ui - q0.x;               // fixed per (thread,k)
        const float dvb  = v0 - q0.y;
        const float C2   = q1.x;                    // ic*cs
        const float C1   = q0.w * du;               // (2*ib*cs)*du
        const float C0   = (q0.z * du) * du;        // (ia*cs)*du^2
        const float coef = q1.y;

        // Phase-separated (m -> exp -> acc): batches the trans pipe, keeps
        // chain temps at 8 wide.
        float m8[SPT];
        #pragma unroll
        for (int e = 0; e < SPT; ++e) {
            const float dv = dvb + (float)e * step;                 // v_add (lit)
            m8[e] = __builtin_fmaf(dv, __builtin_fmaf(C2, dv, C1), C0);  // 2x v_fma (<=0)
        }
        float e8[SPT];
        #pragma unroll
        for (int e = 0; e < SPT; ++e) e8[e] = raw_exp2(m8[e]);      // v_exp_f32
        #pragma unroll
        for (int e = 0; e < SPT; ++e)
            acc[e] = __builtin_fmaf(coef, e8[e], acc[e]);           // v_fma
    }

    // ---- block partial sum -> psum[bb] (plain store, no atomics/zeroing) ----
    float local = 0.0f;
    #pragma unroll
    for (int e = 0; e < SPT; ++e) local += acc[e];
    #pragma unroll
    for (int off = 32; off >= 1; off >>= 1)
        local += __shfl_down(local, off, 64);
    const int wave = tid >> 6;
    const int lane = tid & 63;
    if (lane == 0) s_wsum[wave] = local;
    __syncthreads();
    if (tid == 0) {
        float t = 0.0f;
        #pragma unroll
        for (int w = 0; w < NT1 / 64; ++w) t += s_wsum[w];
        psum[bb] = t;
    }

    // ---- unnormalized store: 2 x dwordx4 per thread, contiguous slice ----
    float4* o4 = reinterpret_cast<float4*>(out + (size_t)b * GG + ((size_t)p << 11));
    o4[2 * tid + 0] = make_float4(acc[0], acc[1], acc[2], acc[3]);
    o4[2 * tid + 1] = make_float4(acc[4], acc[5], acc[6], acc[7]);
}

// Kernel 2 — normalize: scale each batch by 1/sum (ref: where(s>0, s, 1)).
// Memory-bound: reads+writes 16.8 MB each, ~5-6 us. psum reads are
// block-uniform -> scalar loads; kernel boundary makes kernel 1's writes
// visible (same stream).
__global__ __launch_bounds__(NT2) void gmm_hist_norm(
    const float* __restrict__ psum,   // [B*SLICES]
    float* __restrict__ out)          // [B,128,128] in-place
{
    const int bb  = blockIdx.x;       // 0..B*SLICES-1
    const int b   = bb >> 3;
    const int p   = bb & 7;
    const int tid = threadIdx.x;

    float t = 0.0f;
    #pragma unroll
    for (int r = 0; r < SLICES; ++r) t += psum[b * SLICES + r];
    const float inv = (t > 0.0f) ? (1.0f / t) : 1.0f;

    float4* o4 = reinterpret_cast<float4*>(out + (size_t)b * GG + ((size_t)p << 11));
    float4 a = o4[tid];
    float4 c = o4[tid + NT2];
    a.x *= inv; a.y *= inv; a.z *= inv; a.w *= inv;
    c.x *= inv; c.y *= inv; c.z *= inv; c.w *= inv;
    o4[tid]       = a;
    o4[tid + NT2] = c;
}

extern "C" void kernel_launch(void* const* d_in, const int* in_sizes, int n_in,
                              void* d_out, int out_size, void* d_ws, size_t ws_size,
                              hipStream_t stream) {
    const float* mu    = (const float*)d_in[0];
    const float* sigma = (const float*)d_in[1];
    const float* cov12 = (const float*)d_in[2];
    const float* pi_   = (const float*)d_in[3];
    float* out  = (float*)d_out;
    float* psum = (float*)d_ws;   // BB*SLICES floats = 8 KB << ws_size; fully
                                  // overwritten before use (poison-safe)

    hipLaunchKernelGGL(gmm_hist_partial, dim3(BB * SLICES), dim3(NT1), 0, stream,
                       mu, sigma, cov12, pi_, out, psum);
    hipLaunchKernelGGL(gmm_hist_norm, dim3(BB * SLICES), dim3(NT2), 0, stream,
                       psum, out);
}

// Round 2
// 81.883 us; speedup vs baseline: 1.1064x; 1.1064x over previous
//
#include <hip/hip_runtime.h>
#include <math.h>

// Problem constants (match reference)
#define BB   256
#define KK   16
#define NBIN 128
#define GG   (NBIN * NBIN)     // 16384 bins per batch
#define NT   1024              // threads per block
#define SPT  (GG / NT)         // 16 bins per thread

// ---------------------------------------------------------------------------
// Round-2 theory: the kernel is v_exp_f32 THROUGHPUT-bound, not latency-bound.
// Evidence: doubling occupancy (round 1: 8 blocks/CU of 256 thr) changed the
// compute kernel's time by ~0, which rules out wave-latency; per-SIMD pipe
// math (VALU 3.4us, DS 2.6us) explains nothing except a slow trans pipe:
// 1024 wave-exps/SIMD * ~64cyc = 27us == observed kernel time at BOTH
// occupancies. Fix: route 5 of every 8 exps through a VALU polynomial exp2
// (12 VALU ops ~ 24cyc/wave vs ~64cyc trans) so the VALU and trans pipes run
// concurrently. 5/3 split balances: VALU 64+5*24=184 cyc/group vs trans
// 3*64=192 cyc/group.
// ---------------------------------------------------------------------------

// Trans-pipe exp2 (single v_exp_f32). Argument always <= 0; flush-to-zero
// underflow matches reference exp(-huge) -> 0.
__device__ __forceinline__ float raw_exp2(float x) {
#if __has_builtin(__builtin_amdgcn_exp2f)
    return __builtin_amdgcn_exp2f(x);
#else
    float r;
    asm volatile("v_exp_f32 %0, %1\n\ts_nop 1" : "=v"(r) : "v"(x));
    return r;
#endif
}

// VALU-pipe exp2 for x <= 0. Magic-number range reduction: n = rne(x),
// f = x - n in [-0.5, 0.5]; Cephes deg-6 poly for 2^f (rel err ~2e-7);
// exponent reassembly by integer add (exact: low 9 bits of magic are 0, so
// (t_bits << 23) == n << 23 mod 2^32). Clamp at -48: 2^-48 * coef_max(159)
// / s(~5e3) ~ 1e-16 per bin -- far below tolerance; result stays normal.
// Cost: ~12 VALU instrs, zero trans.
__device__ __forceinline__ float poly_exp2(float x) {
    const float magic = 12582912.0f;            // 1.5 * 2^23
    const float xc = fmaxf(x, -48.0f);
    const float t  = xc + magic;                // n = rne(xc) in low mantissa
    const float f  = xc - (t - magic);          // f in [-0.5, 0.5], exact
    float p =                      1.535336188319500e-4f;
    p = __builtin_fmaf(p, f, 1.339887440266574e-3f);
    p = __builtin_fmaf(p, f, 9.618437357674640e-3f);
    p = __builtin_fmaf(p, f, 5.550332471162809e-2f);
    p = __builtin_fmaf(p, f, 2.402264791363012e-1f);
    p = __builtin_fmaf(p, f, 6.931472028550421e-1f);
    p = __builtin_fmaf(p, f, 1.0f);             // 2^f
    const int rb = __float_as_int(p) + (__float_as_int(t) << 23);  // * 2^n
    return __int_as_float(rb);
}

// One block per batch (normalization needs the whole batch in one workgroup).
// Thread t owns bins g = s*1024 + t (s=0..15):
//   j = g & 127  (constant per thread)  -> dv fixed per (thread,k)
//   i = 8*s + (t>>7)                    -> du = base_k + 8*s*step
// Coalesced stores: for fixed s, consecutive tids hit consecutive addresses.
// Verified structure from the 76.8us baseline; ONLY the exp phase changed.
__global__ __launch_bounds__(NT) void gmm_hist_kernel(
    const float* __restrict__ mu,     // [B,K,2]
    const float* __restrict__ sigma,  // [B,K,2]
    const float* __restrict__ cov12,  // [B,K]
    const float* __restrict__ pi_,    // [B,K]
    float* __restrict__ out)          // [B,128,128]
{
    const int b   = blockIdx.x;
    const int tid = threadIdx.x;

    // Per-mixture params packed for ds_read_b128:
    //   s_par[2k+0] = {mu_u, mu_v, ia*cs, 2*ib*cs}
    //   s_par[2k+1] = {ic*cs, coef, 0, 0}
    __shared__ float4 s_par[2 * KK];
    __shared__ float  s_wsum[NT / 64];
    __shared__ float  s_total;

    // ---- per-mixture precompute (threads 0..15), mirrors reference exactly ----
    if (tid < KK) {
        const int idx = b * KK + tid;
        const float m_u = mu[idx * 2 + 0];
        const float m_v = mu[idx * 2 + 1];
        const float su  = fmaxf(sigma[idx * 2 + 0], 0.001f);
        const float sv  = fmaxf(sigma[idx * 2 + 1], 0.001f);
        const float su2 = su * su;
        const float sv2 = sv * sv;
        const float c11 = su2 + 1e-6f;
        const float c22 = sv2 + 1e-6f;
        const float off = cov12[idx];
        const float det_full = c11 * c22 - off * off;
        const bool  valid    = (det_full > 0.0f);   // NaN compares false -> fallback
        const float det_safe = valid ? det_full : 1.0f;
        const float ia  = valid ? (c22 / det_safe) : (1.0f / su2);
        const float ib  = valid ? (-off / det_safe) : 0.0f;
        const float ic  = valid ? (c11 / det_safe) : (1.0f / sv2);
        const float det = valid ? det_full : (su2 * sv2);
        const float coef = pi_[idx] / (6.283185307179586f * sqrtf(det + 1e-6f));
        const float cs = -0.7213475204444817f;      // -0.5 * log2(e), folded
        s_par[2 * tid + 0] = make_float4(m_u, m_v, ia * cs, (2.0f * ib) * cs);
        s_par[2 * tid + 1] = make_float4(ic * cs, coef, 0.0f, 0.0f);
    }
    __syncthreads();

    const float step = 4.0f / 127.0f;               // linspace(-2,2,128) step
    const int   j    = tid & (NBIN - 1);
    const int   i0   = tid >> 7;                    // 0..7
    const float gv   = -2.0f + (float)j * step;
    const float u0   = -2.0f + (float)i0 * step;    // row coord at s=0

    float acc[SPT];
    #pragma unroll
    for (int s = 0; s < SPT; ++s) acc[s] = 0.0f;

    // ---- main accumulation: 16 mixtures x 16 bins per thread ----
    // Body per eval: v_add(du) + v_fma + v_fma + exp + v_fma.
    // Direct quadratic-form evaluation (NOT expanded in s): expanded forms
    // cancel catastrophically for narrow Gaussians (ia up to ~1e6).
    #pragma unroll
    for (int k = 0; k < KK; ++k) {
        const float4 p0 = s_par[2 * k + 0];         // ds_read_b128
        const float4 p1 = s_par[2 * k + 1];         // ds_read_b128
        const float dv   = gv - p0.y;
        const float ia   = p0.z;                    // pre-scaled by -0.5*log2e
        const float Bp   = p0.w * dv;
        const float Ap   = p1.x * (dv * dv);
        const float coef = p1.y;
        const float base = u0 - p0.x;               // du at s=0

        // Two groups of 8: phase-separated (m -> exp -> acc). Exp phase is
        // pipe-split: 3 evals on the trans pipe (issued first -- long pipe),
        // 5 on the VALU poly path, so both throughput pipes stay busy.
        #pragma unroll
        for (int h = 0; h < SPT; h += 8) {
            float m8[8];
            #pragma unroll
            for (int t = 0; t < 8; ++t) {
                const float du = base + (float)(8 * (h + t)) * step;  // v_add (lit)
                const float tt = __builtin_fmaf(ia, du, Bp);          // v_fma
                m8[t] = __builtin_fmaf(du, tt, Ap);                   // v_fma (<= 0)
            }
            float e8[8];
            e8[5] = raw_exp2(m8[5]);                                  // trans pipe
            e8[6] = raw_exp2(m8[6]);
            e8[7] = raw_exp2(m8[7]);
            #pragma unroll
            for (int t = 0; t < 5; ++t) e8[t] = poly_exp2(m8[t]);     // VALU pipe
            #pragma unroll
            for (int t = 0; t < 8; ++t)
                acc[h + t] = __builtin_fmaf(coef, e8[t], acc[h + t]); // v_fma
        }
    }

    // ---- block-wide sum for per-batch normalization ----
    float local = 0.0f;
    #pragma unroll
    for (int s = 0; s < SPT; ++s) local += acc[s];

    #pragma unroll
    for (int off = 32; off >= 1; off >>= 1)
        local += __shfl_down(local, off, 64);

    const int wave = tid >> 6;
    const int lane = tid & 63;
    if (lane == 0) s_wsum[wave] = local;
    __syncthreads();

    if (tid == 0) {
        float t = 0.0f;
        #pragma unroll
        for (int w = 0; w < NT / 64; ++w) t += s_wsum[w];
        s_total = (t > 0.0f) ? t : 1.0f;                    // ref: where(s>0, s, 1)
    }
    __syncthreads();

    const float inv = 1.0f / s_total;
    float* outb = out + (size_t)b * GG;
    #pragma unroll
    for (int s = 0; s < SPT; ++s)
        outb[s * NT + tid] = acc[s] * inv;                  // coalesced dword stores
}

extern "C" void kernel_launch(void* const* d_in, const int* in_sizes, int n_in,
                              void* d_out, int out_size, void* d_ws, size_t ws_size,
                              hipStream_t stream) {
    const float* mu    = (const float*)d_in[0];
    const float* sigma = (const float*)d_in[1];
    const float* cov12 = (const float*)d_in[2];
    const float* pi_   = (const float*)d_in[3];
    float* out = (float*)d_out;

    hipLaunchKernelGGL(gmm_hist_kernel, dim3(BB), dim3(NT), 0, stream,
                       mu, sigma, cov12, pi_, out);
}

// Round 4
// 78.277 us; speedup vs baseline: 1.1574x; 1.0461x over previous
//
#include <hip/hip_runtime.h>
#include <math.h>

// Problem constants (match reference)
#define BB   256
#define KK   16
#define NBIN 128
#define GG   (NBIN * NBIN)     // 16384 bins per batch
#define NT   1024              // threads per block
#define SPT  (GG / NT)         // 16 bins per thread

// ---------------------------------------------------------------------------
// Round-4: packed FP32 (VOP3P), operands fixed. R3's compile failure was
// operand CLASS, not the instruction: gfx950 has v_pk_fma_f32/v_pk_add_f32
// but every operand must be a 64-bit VGPR pair (the assembler rejected the
// single-VGPR scalars my op_sel_hi broadcast passed). Fix: materialize
// per-mixture scalars as true {x,x} pairs (few movs per k, hoisted), default
// packed modifiers. Per 2 evals: 1 pk_add + 2 pk_fma + 2 v_exp + 2 scalar
// acc-fma => main-loop VALU ~1150 -> ~880/thread (-24%), bitwise-identical
// arithmetic (same literal du offsets, same fl() fma ops).
// Evidence so far: R1 2x occupancy -> null (not latency-bound); R2 trans cut
// -> null, VALU add -> proportional cost (VALU issue on critical path).
// This round's magnitude discriminates "time ~ instr count" (expect ~-7us)
// vs "fixed dispatch overhead" (expect ~0).
// ---------------------------------------------------------------------------

typedef float f32x2 __attribute__((ext_vector_type(2)));

// All-pair packed ops, default modifiers (op_sel_hi=[1,1,1] = plain packed).
__device__ __forceinline__ f32x2 pk_fma(f32x2 a, f32x2 b, f32x2 c) {
    f32x2 d;
    asm("v_pk_fma_f32 %0, %1, %2, %3" : "=v"(d) : "v"(a), "v"(b), "v"(c));
    return d;
}
__device__ __forceinline__ f32x2 pk_add(f32x2 a, f32x2 b) {
    f32x2 d;
    asm("v_pk_add_f32 %0, %1, %2" : "=v"(d) : "v"(a), "v"(b));
    return d;
}

// Trans-pipe exp2 (single v_exp_f32). Argument always <= 0; flush-to-zero
// underflow matches reference exp(-huge) -> 0.
__device__ __forceinline__ float raw_exp2(float x) {
#if __has_builtin(__builtin_amdgcn_exp2f)
    return __builtin_amdgcn_exp2f(x);
#else
    float r;
    asm volatile("v_exp_f32 %0, %1\n\ts_nop 1" : "=v"(r) : "v"(x));
    return r;
#endif
}

// One block per batch (normalization needs the whole batch in one workgroup).
// Thread t owns bins g = s*1024 + t (s=0..15):
//   j = g & 127  (constant per thread)  -> dv fixed per (thread,k)
//   i = 8*s + (t>>7)                    -> du = base_k + 8*s*step
// Coalesced stores: for fixed s, consecutive tids hit consecutive addresses.
// Verified R0 structure; ONLY the m-computation is packed (pairwise in s).
__global__ __launch_bounds__(NT) void gmm_hist_kernel(
    const float* __restrict__ mu,     // [B,K,2]
    const float* __restrict__ sigma,  // [B,K,2]
    const float* __restrict__ cov12,  // [B,K]
    const float* __restrict__ pi_,    // [B,K]
    float* __restrict__ out)          // [B,128,128]
{
    const int b   = blockIdx.x;
    const int tid = threadIdx.x;

    // Per-mixture params packed for ds_read_b128:
    //   s_par[2k+0] = {mu_u, mu_v, ia*cs, 2*ib*cs}
    //   s_par[2k+1] = {ic*cs, coef, 0, 0}
    __shared__ float4 s_par[2 * KK];
    __shared__ float  s_wsum[NT / 64];
    __shared__ float  s_total;

    // ---- per-mixture precompute (threads 0..15), mirrors reference exactly ----
    if (tid < KK) {
        const int idx = b * KK + tid;
        const float m_u = mu[idx * 2 + 0];
        const float m_v = mu[idx * 2 + 1];
        const float su  = fmaxf(sigma[idx * 2 + 0], 0.001f);
        const float sv  = fmaxf(sigma[idx * 2 + 1], 0.001f);
        const float su2 = su * su;
        const float sv2 = sv * sv;
        const float c11 = su2 + 1e-6f;
        const float c22 = sv2 + 1e-6f;
        const float off = cov12[idx];
        const float det_full = c11 * c22 - off * off;
        const bool  valid    = (det_full > 0.0f);   // NaN compares false -> fallback
        const float det_safe = valid ? det_full : 1.0f;
        const float ia  = valid ? (c22 / det_safe) : (1.0f / su2);
        const float ib  = valid ? (-off / det_safe) : 0.0f;
        const float ic  = valid ? (c11 / det_safe) : (1.0f / sv2);
        const float det = valid ? det_full : (su2 * sv2);
        const float coef = pi_[idx] / (6.283185307179586f * sqrtf(det + 1e-6f));
        const float cs = -0.7213475204444817f;      // -0.5 * log2(e), folded
        s_par[2 * tid + 0] = make_float4(m_u, m_v, ia * cs, (2.0f * ib) * cs);
        s_par[2 * tid + 1] = make_float4(ic * cs, coef, 0.0f, 0.0f);
    }
    __syncthreads();

    const float step = 4.0f / 127.0f;               // linspace(-2,2,128) step
    const int   j    = tid & (NBIN - 1);
    const int   i0   = tid >> 7;                    // 0..7
    const float gv   = -2.0f + (float)j * step;
    const float u0   = -2.0f + (float)i0 * step;    // row coord at s=0

    // du offsets for s-pairs (2q, 2q+1): SAME compile-time literals as the
    // scalar R0 kernel ((float)(8*s) * step), materialized once as pairs.
    f32x2 off2[SPT / 2];
    #pragma unroll
    for (int q = 0; q < SPT / 2; ++q) {
        off2[q].x = (float)(16 * q) * step;
        off2[q].y = (float)(16 * q + 8) * step;
    }

    float acc[SPT];
    #pragma unroll
    for (int s = 0; s < SPT; ++s) acc[s] = 0.0f;

    // ---- main accumulation: 16 mixtures x 16 bins per thread ----
    // Per s-pair: pk_add(du) + pk_fma + pk_fma -> m pair; then batched exp
    // and scalar acc fma (packing acc would cost movs, not save them).
    // Direct quadratic-form evaluation (NOT expanded in s): expanded forms
    // cancel catastrophically for narrow Gaussians (ia up to ~1e6).
    #pragma unroll
    for (int k = 0; k < KK; ++k) {
        const float4 p0 = s_par[2 * k + 0];         // ds_read_b128
        const float4 p1 = s_par[2 * k + 1];         // ds_read_b128
        const float dv   = gv - p0.y;
        const float Bp   = p0.w * dv;               // (2*ib*cs)*dv
        const float Ap   = p1.x * (dv * dv);        // (ic*cs)*dv^2
        const float coef = p1.y;
        const float base = u0 - p0.x;               // du at s=0

        f32x2 ia2, Bp2, Ap2, base2;
        ia2.x   = p0.z;  ia2.y   = p0.z;            // (ia*cs) broadcast pair
        Bp2.x   = Bp;    Bp2.y   = Bp;
        Ap2.x   = Ap;    Ap2.y   = Ap;
        base2.x = base;  base2.y = base;

        // Two groups of 8: phase-separated (m -> exp -> acc) so the trans
        // pipe gets batched work and chain temps stay at 8 wide.
        #pragma unroll
        for (int h = 0; h < SPT; h += 8) {
            float m8[8];
            #pragma unroll
            for (int p = 0; p < 4; ++p) {
                const f32x2 du2 = pk_add(base2, off2[h / 2 + p]); // v_pk_add
                const f32x2 q2  = pk_fma(ia2, du2, Bp2);          // v_pk_fma
                const f32x2 m2  = pk_fma(du2, q2, Ap2);           // v_pk_fma (<=0)
                m8[2 * p]     = m2.x;
                m8[2 * p + 1] = m2.y;
            }
            float e8[8];
            #pragma unroll
            for (int t = 0; t < 8; ++t) e8[t] = raw_exp2(m8[t]);      // v_exp_f32
            #pragma unroll
            for (int t = 0; t < 8; ++t)
                acc[h + t] = __builtin_fmaf(coef, e8[t], acc[h + t]); // v_fma
        }
    }

    // ---- block-wide sum for per-batch normalization ----
    float local = 0.0f;
    #pragma unroll
    for (int s = 0; s < SPT; ++s) local += acc[s];

    #pragma unroll
    for (int off = 32; off >= 1; off >>= 1)
        local += __shfl_down(local, off, 64);

    const int wave = tid >> 6;
    const int lane = tid & 63;
    if (lane == 0) s_wsum[wave] = local;
    __syncthreads();

    if (tid == 0) {
        float t = 0.0f;
        #pragma unroll
        for (int w = 0; w < NT / 64; ++w) t += s_wsum[w];
        s_total = (t > 0.0f) ? t : 1.0f;                    // ref: where(s>0, s, 1)
    }
    __syncthreads();

    const float inv = 1.0f / s_total;
    float* outb = out + (size_t)b * GG;
    #pragma unroll
    for (int s = 0; s < SPT; ++s)
        outb[s * NT + tid] = acc[s] * inv;                  // coalesced dword stores
}

extern "C" void kernel_launch(void* const* d_in, const int* in_sizes, int n_in,
                              void* d_out, int out_size, void* d_ws, size_t ws_size,
                              hipStream_t stream) {
    const float* mu    = (const float*)d_in[0];
    const float* sigma = (const float*)d_in[1];
    const float* cov12 = (const float*)d_in[2];
    const float* pi_   = (const float*)d_in[3];
    float* out = (float*)d_out;

    hipLaunchKernelGGL(gmm_hist_kernel, dim3(BB), dim3(NT), 0, stream,
                       mu, sigma, cov12, pi_, out);
}